// Round 6
// baseline (232.511 us; speedup 1.0000x reference)
//
#include <hip/hip_runtime.h>

// T=8, L=2e6, B=16384. Outputs (flat f32 concat): [0] indices 16M, [1] offsets 131073, [2] weights 16M.
constexpr long NA = 16000000;   // T*L
constexpr long NB = 131073;     // T*B+1
constexpr int  BLK = 256;
constexpr int  UNR = 8;                                   // 16B chunks per thread (128 B in flight)
constexpr int  CHUNKS = 4000000;                          // 16B chunks per big region (16M * 4B / 16B)
constexpr int  GA = (CHUNKS + BLK * UNR - 1) / (BLK * UNR);  // 1954 blocks (indices)
constexpr int  GC = GA;                                      // 1954 blocks (weights)
constexpr int  GB = ((int)NB + BLK - 1) / BLK;               // 513 blocks (offsets)

// clang vector types: accepted by __builtin_nontemporal_* (HIP_vector_type is not).
typedef int   v4i   __attribute__((ext_vector_type(4)));
typedef float v4f   __attribute__((ext_vector_type(4)));
// 16-byte store with only 4-byte alignment: global_store_dwordx4 needs only dword
// alignment, so one instruction covers the out-region misaligned by 1 float.
typedef float v4f_u __attribute__((ext_vector_type(4), aligned(4)));

__global__ __launch_bounds__(BLK) void tbe_prep(
    const int* __restrict__ indices,
    const int* __restrict__ offsets,
    const float* __restrict__ weights,
    float* __restrict__ out) {
  const int bid = blockIdx.x;
  const int tid = threadIdx.x;

  if (bid < GA) {
    // ---- Output 0: indices int32 -> f32 (exact). Cached loads (inputs are L3-resident
    // after the harness restore-copy); nontemporal streaming stores. ----
    const v4i* p = (const v4i*)indices;
    v4f* o = (v4f*)out;
    const int base = bid * (BLK * UNR) + tid;
    v4i a[UNR];
#pragma unroll
    for (int u = 0; u < UNR; ++u) {
      int c = base + u * BLK;
      if (c < CHUNKS) a[u] = p[c];
    }
#pragma unroll
    for (int u = 0; u < UNR; ++u) {
      int c = base + u * BLK;
      if (c < CHUNKS) {
        v4f r;
        r.x = (float)a[u].x; r.y = (float)a[u].y;
        r.z = (float)a[u].z; r.w = (float)a[u].w;
        __builtin_nontemporal_store(r, &o[c]);
      }
    }
  } else if (bid < GA + GC) {
    // ---- Output 2: weights f32 copy; out region starts at element NA+NB (== 1 mod 4) ----
    const v4f* p = (const v4f*)weights;
    v4f_u* o = (v4f_u*)(out + (NA + NB));   // 4B-aligned 16B nt stores
    const int base = (bid - GA) * (BLK * UNR) + tid;
    v4f a[UNR];
#pragma unroll
    for (int u = 0; u < UNR; ++u) {
      int c = base + u * BLK;
      if (c < CHUNKS) a[u] = p[c];
    }
#pragma unroll
    for (int u = 0; u < UNR; ++u) {
      int c = base + u * BLK;
      if (c < CHUNKS) __builtin_nontemporal_store(a[u], &o[c]);
    }
  } else {
    // ---- Output 1: combined_offsets, scalar (131,073 elements, negligible) ----
    long j = (long)(bid - GA - GC) * BLK + tid;
    if (j < NB) {
      int v;
      if (j == NB - 1) {
        v = 16000000;                            // T*L sentinel
      } else {
        int t = (int)(j >> 14);                  // j / B
        int k = (int)(j & 16383);                // j % B
        v = offsets[t * 16385 + k] + t * 2000000;
      }
      out[NA + j] = (float)v;
    }
  }
}

extern "C" void kernel_launch(void* const* d_in, const int* in_sizes, int n_in,
                              void* d_out, int out_size, void* d_ws, size_t ws_size,
                              hipStream_t stream) {
  const int*   indices = (const int*)d_in[0];
  const int*   offsets = (const int*)d_in[1];
  const float* weights = (const float*)d_in[2];
  float*       out     = (float*)d_out;

  const int grid = GA + GC + GB;  // 4,421 blocks
  tbe_prep<<<dim3(grid), dim3(BLK), 0, stream>>>(indices, offsets, weights, out);
}

// Round 7
// 221.972 us; speedup vs baseline: 1.0475x; 1.0475x over previous
//
#include <hip/hip_runtime.h>

// T=8, L=2e6, B=16384. Outputs (flat f32 concat): [0] indices 16M, [1] offsets 131073, [2] weights 16M.
constexpr long NA   = 16000000;   // T*L
constexpr long NB   = 131073;     // T*B+1
constexpr int  BLK  = 256;
constexpr int  UNR  = 4;          // 16B chunks per thread per iteration
constexpr int  HALF = 4000000;    // 16B chunks per big region (16M elems * 4B / 16B)
constexpr int  NBLK_PER = 1024;   // grid-stride blocks per big region (4/CU)
constexpr int  SEG  = BLK * UNR;  // 1024 chunks per block-iteration
constexpr int  GB   = ((int)NB + BLK - 1) / BLK;  // 513 offset blocks

// clang vector types: accepted by __builtin_nontemporal_* (HIP_vector_type is not).
typedef int   v4i   __attribute__((ext_vector_type(4)));
typedef float v4f   __attribute__((ext_vector_type(4)));
// 16-byte store with only 4-byte alignment: global_store_dwordx4 needs only dword
// alignment, so one instruction covers the out-region misaligned by 1 float.
typedef float v4f_u __attribute__((ext_vector_type(4), aligned(4)));

__global__ __launch_bounds__(BLK) void tbe_prep(
    const int* __restrict__ indices,
    const int* __restrict__ offsets,
    const float* __restrict__ weights,
    float* __restrict__ out) {
  const int bid = blockIdx.x;
  const int tid = threadIdx.x;

  if (bid < NBLK_PER) {
    // ---- Output 0: indices int32 -> f32 (exact). Persistent grid-stride loop:
    // next iteration's loads overlap previous iteration's store drain. ----
    const v4i* p = (const v4i*)indices;
    v4f* o = (v4f*)out;
    for (int base = bid * SEG; base < HALF; base += NBLK_PER * SEG) {
      v4i a[UNR];
#pragma unroll
      for (int u = 0; u < UNR; ++u) {
        int c = base + tid + u * BLK;
        if (c < HALF) a[u] = __builtin_nontemporal_load(&p[c]);
      }
#pragma unroll
      for (int u = 0; u < UNR; ++u) {
        int c = base + tid + u * BLK;
        if (c < HALF) {
          v4f r;
          r.x = (float)a[u].x; r.y = (float)a[u].y;
          r.z = (float)a[u].z; r.w = (float)a[u].w;
          o[c] = r;
        }
      }
    }
  } else if (bid < 2 * NBLK_PER) {
    // ---- Output 2: weights f32 copy; out region starts at element NA+NB (== 1 mod 4) ----
    const v4f* p = (const v4f*)weights;
    v4f_u* o = (v4f_u*)(out + (NA + NB));   // 4B-aligned 16B stores
    for (int base = (bid - NBLK_PER) * SEG; base < HALF; base += NBLK_PER * SEG) {
      v4f a[UNR];
#pragma unroll
      for (int u = 0; u < UNR; ++u) {
        int c = base + tid + u * BLK;
        if (c < HALF) a[u] = __builtin_nontemporal_load(&p[c]);
      }
#pragma unroll
      for (int u = 0; u < UNR; ++u) {
        int c = base + tid + u * BLK;
        if (c < HALF) o[c] = a[u];
      }
    }
  } else {
    // ---- Output 1: combined_offsets, scalar (131,073 elements, negligible) ----
    long j = (long)(bid - 2 * NBLK_PER) * BLK + tid;
    if (j < NB) {
      int v;
      if (j == NB - 1) {
        v = 16000000;                            // T*L sentinel
      } else {
        int t = (int)(j >> 14);                  // j / B
        int k = (int)(j & 16383);                // j % B
        v = offsets[t * 16385 + k] + t * 2000000;
      }
      out[NA + j] = (float)v;
    }
  }
}

extern "C" void kernel_launch(void* const* d_in, const int* in_sizes, int n_in,
                              void* d_out, int out_size, void* d_ws, size_t ws_size,
                              hipStream_t stream) {
  const int*   indices = (const int*)d_in[0];
  const int*   offsets = (const int*)d_in[1];
  const float* weights = (const float*)d_in[2];
  float*       out     = (float*)d_out;

  const int grid = 2 * NBLK_PER + GB;  // 2,561 blocks
  tbe_prep<<<dim3(grid), dim3(BLK), 0, stream>>>(indices, offsets, weights, out);
}